// Round 2
// baseline (655.279 us; speedup 1.0000x reference)
//
#include <hip/hip_runtime.h>
#include <hip/hip_bf16.h>
#include <cstdint>

#define NN   512
#define CZ   128
#define PTOT (NN * NN)

typedef unsigned short u16;
typedef unsigned int   u32;

using f32x4  = __attribute__((ext_vector_type(4))) float;
using bf16x8 = __attribute__((ext_vector_type(8))) __bf16;

__device__ __forceinline__ u16 f2bf(float x) {
    u32 u = __float_as_uint(x);
    u = (u + 0x7fffu + ((u >> 16) & 1u)) >> 16;
    return (u16)u;
}

__device__ __forceinline__ f32x4 mfma16(bf16x8 a, bf16x8 b, f32x4 c) {
    return __builtin_amdgcn_mfma_f32_16x16x32_bf16(a, b, c, 0, 0, 0);
}

#define GLDS16(src, dst) __builtin_amdgcn_global_load_lds(                  \
        (__attribute__((address_space(1))) void*)(src),                     \
        (__attribute__((address_space(3))) void*)(dst), 16, 0, 0)

// ---------------------------------------------------------------------------
// Kernel 0: weight prep. Wt[m][n][k] = W_m[k][n] as bf16.
// m = 0..3 : W_ap, W_ag, W_bp, W_bg ; m = 4 : W_z
// ---------------------------------------------------------------------------
__global__ __launch_bounds__(256) void prep_w(
    const float* __restrict__ w0, const float* __restrict__ w1,
    const float* __restrict__ w2, const float* __restrict__ w3,
    const float* __restrict__ w4, u16* __restrict__ out)
{
    const float* srcs[5] = {w0, w1, w2, w3, w4};
    const float* src = srcs[blockIdx.x];
    u16* dst = out + blockIdx.x * 16384;
    for (int idx = threadIdx.x; idx < 16384; idx += 256) {
        int n = idx >> 7, k = idx & 127;
        dst[idx] = f2bf(src[k * 128 + n]);
    }
}

// ---------------------------------------------------------------------------
// Kernel 1: LayerNorm + pair-projection + sigmoid gate + mask, transposed store.
// flavor 0: tile = (i=ir, k=k0..k0+63) -> a -> Aout[c][i][k]
// flavor 1: tile = (k=k0..k0+63, j=ir) -> b -> Bout[c][j][k]
// ---------------------------------------------------------------------------
__global__ __launch_bounds__(256) void ln_proj(
    const float* __restrict__ z,    const float* __restrict__ mask,
    const float* __restrict__ lnw,  const float* __restrict__ lnb,
    const u16*   __restrict__ Wt,
    const float* __restrict__ b_ap, const float* __restrict__ b_ag,
    const float* __restrict__ b_bp, const float* __restrict__ b_bg,
    u16* __restrict__ Aout, u16* __restrict__ Bout)
{
    __shared__ u16  zn[64 * 128];    // [row][128 ch], 16B-unit XOR swizzled
    __shared__ u16  tbuf[128 * 72];  // [hid ch][64 rows], stride 72
    __shared__ float lmask[64];

    const int t    = threadIdx.x;
    const int tile = blockIdx.x;
    const int flav = blockIdx.y;
    const int ir   = tile >> 3;
    const int k0   = (tile & 7) << 6;

    // ---- LayerNorm: 4 threads per row, 32 channels each ----
    const int r = t >> 2, q = t & 3;
    const long prow = flav ? ((long)(k0 + r) * NN + ir) : ((long)ir * NN + k0 + r);
    const float4* zp = (const float4*)(z + prow * CZ + q * 32);

    float v[32];
    float s = 0.f, s2 = 0.f;
#pragma unroll
    for (int j = 0; j < 8; ++j) {
        float4 x = zp[j];
        v[j * 4 + 0] = x.x; v[j * 4 + 1] = x.y;
        v[j * 4 + 2] = x.z; v[j * 4 + 3] = x.w;
        s  += x.x + x.y + x.z + x.w;
        s2 += x.x * x.x + x.y * x.y + x.z * x.z + x.w * x.w;
    }
    s  += __shfl_xor(s, 1);  s  += __shfl_xor(s, 2);
    s2 += __shfl_xor(s2, 1); s2 += __shfl_xor(s2, 2);
    float mu  = s * (1.f / 128.f);
    float var = s2 * (1.f / 128.f) - mu * mu;
    float rs  = rsqrtf(var + 1e-5f);

#pragma unroll
    for (int uu = 0; uu < 4; ++uu) {
        int u = q * 4 + uu;
        uint4 w4;
        u32 pk[4];
#pragma unroll
        for (int e2 = 0; e2 < 4; ++e2) {
            int cl = uu * 8 + e2 * 2;
            int c  = q * 32 + cl;
            float a0 = (v[cl]     - mu) * rs * lnw[c]     + lnb[c];
            float a1 = (v[cl + 1] - mu) * rs * lnw[c + 1] + lnb[c + 1];
            pk[e2] = (u32)f2bf(a0) | ((u32)f2bf(a1) << 16);
        }
        w4.x = pk[0]; w4.y = pk[1]; w4.z = pk[2]; w4.w = pk[3];
        *(uint4*)&zn[(r << 7) + ((u ^ (r & 15)) << 3)] = w4;
    }
    if (q == 0) lmask[r] = mask[prow];
    __syncthreads();

    // ---- GEMM: M=64 rows x (2 matrices x 32 cols per wave), K=128 ----
    const int l = t & 63, w = t >> 6;
    const u16* Wp = Wt + (flav * 2 + 0) * 16384;
    const u16* Wg = Wt + (flav * 2 + 1) * 16384;

    f32x4 zero4 = {0.f, 0.f, 0.f, 0.f};
    f32x4 accP[4][2], accG[4][2];
#pragma unroll
    for (int mf = 0; mf < 4; ++mf)
#pragma unroll
        for (int nf = 0; nf < 2; ++nf) { accP[mf][nf] = zero4; accG[mf][nf] = zero4; }

#pragma unroll
    for (int kk = 0; kk < 4; ++kk) {
        bf16x8 af[4];
#pragma unroll
        for (int mf = 0; mf < 4; ++mf) {
            int row = (mf << 4) + (l & 15);
            int su  = (kk * 4 + (l >> 4)) ^ (row & 15);
            af[mf] = *(const bf16x8*)&zn[(row << 7) + (su << 3)];
        }
#pragma unroll
        for (int nf = 0; nf < 2; ++nf) {
            int n  = (w << 5) + (nf << 4) + (l & 15);
            int ko = (kk << 5) + ((l >> 4) << 3);
            bf16x8 bp = *(const bf16x8*)&Wp[(n << 7) + ko];
            bf16x8 bg = *(const bf16x8*)&Wg[(n << 7) + ko];
#pragma unroll
            for (int mf = 0; mf < 4; ++mf) {
                accP[mf][nf] = mfma16(af[mf], bp, accP[mf][nf]);
                accG[mf][nf] = mfma16(af[mf], bg, accG[mf][nf]);
            }
        }
    }

    // ---- gate + mask, write transposed [hid][row] ----
    const float* bPp = flav ? b_bp : b_ap;
    const float* bGp = flav ? b_bg : b_ag;
#pragma unroll
    for (int nf = 0; nf < 2; ++nf) {
        int col = (w << 5) + (nf << 4) + (l & 15);
        float bp = bPp[col], bg = bGp[col];
#pragma unroll
        for (int mf = 0; mf < 4; ++mf) {
#pragma unroll
            for (int rg = 0; rg < 4; ++rg) {
                int row = (mf << 4) + ((l >> 4) << 2) + rg;
                float pv = accP[mf][nf][rg] + bp;
                float gv = accG[mf][nf][rg] + bg;
                float av = pv * (1.f / (1.f + __expf(-gv))) * lmask[row];
                tbuf[col * 72 + row] = f2bf(av);
            }
        }
    }
    __syncthreads();

    // ---- coalesced store: out[c][ir][k0 + 0..63] ----
    u16* outp = flav ? Bout : Aout;
    const int c = t >> 1, half = t & 1;
    u16* dst = outp + (size_t)c * PTOT + (size_t)ir * NN + k0 + half * 32;
    const u16* srcb = &tbuf[c * 72 + half * 32];
#pragma unroll
    for (int e = 0; e < 4; ++e)
        *(uint4*)(dst + e * 8) = *(const uint4*)(srcb + e * 8);
}

// ---------------------------------------------------------------------------
// Kernel 2: per-channel GEMM  O[c][i][j] = sum_k A[c][i][k] * B[c][j][k]
// 128x128 tile, BK=64, double-buffered global_load_lds, source-side XOR swizzle.
// ---------------------------------------------------------------------------
__global__ __launch_bounds__(256) void cgemm(
    const u16* __restrict__ A, const u16* __restrict__ B, u16* __restrict__ O)
{
    __shared__ u16 ldsA[2][128 * 64];
    __shared__ u16 ldsB[2][128 * 64];

    const int t = threadIdx.x, l = t & 63, w = t >> 6;
    const int bx = blockIdx.x;
    const int c  = bx >> 4, ti = (bx >> 2) & 3, tj = bx & 3;
    const u16* Ab = A + (size_t)c * PTOT + (size_t)(ti * 128) * NN;
    const u16* Bb = B + (size_t)c * PTOT + (size_t)(tj * 128) * NN;

    const int lr8 = (w << 3) + (l >> 3);  // wave-local row within 32-row round
    const int uu  = l & 7;                // 16B unit

    auto stage = [&](int buf, int kt) {
#pragma unroll
        for (int ri = 0; ri < 4; ++ri) {
            int row = ri * 32 + lr8;
            const u16* sa = Ab + (size_t)row * NN + (kt << 6) + ((uu ^ (row & 7)) << 3);
            const u16* sb = Bb + (size_t)row * NN + (kt << 6) + ((uu ^ (row & 7)) << 3);
            u16* da = &ldsA[buf][(ri * 32 + (w << 3)) << 6];
            u16* db = &ldsB[buf][(ri * 32 + (w << 3)) << 6];
            GLDS16(sa, da);
            GLDS16(sb, db);
        }
    };

    const int wm = w >> 1, wn = w & 1;
    f32x4 zero4 = {0.f, 0.f, 0.f, 0.f};
    f32x4 acc[4][4];
#pragma unroll
    for (int mf = 0; mf < 4; ++mf)
#pragma unroll
        for (int nf = 0; nf < 4; ++nf) acc[mf][nf] = zero4;

    stage(0, 0);
    __syncthreads();
    int cur = 0;
    for (int kt = 0; kt < 8; ++kt) {
        if (kt < 7) stage(cur ^ 1, kt + 1);
        const u16* lA = ldsA[cur];
        const u16* lB = ldsB[cur];
#pragma unroll
        for (int kk = 0; kk < 2; ++kk) {
            bf16x8 af[4], bfr[4];
#pragma unroll
            for (int mf = 0; mf < 4; ++mf) {
                int row = (wm << 6) + (mf << 4) + (l & 15);
                int su  = ((kk << 2) + (l >> 4)) ^ (row & 7);
                af[mf] = *(const bf16x8*)&lA[(row << 6) + (su << 3)];
            }
#pragma unroll
            for (int nf = 0; nf < 4; ++nf) {
                int row = (wn << 6) + (nf << 4) + (l & 15);
                int su  = ((kk << 2) + (l >> 4)) ^ (row & 7);
                bfr[nf] = *(const bf16x8*)&lB[(row << 6) + (su << 3)];
            }
#pragma unroll
            for (int mf = 0; mf < 4; ++mf)
#pragma unroll
                for (int nf = 0; nf < 4; ++nf)
                    acc[mf][nf] = mfma16(af[mf], bfr[nf], acc[mf][nf]);
        }
        if (kt < 7) __syncthreads();
        cur ^= 1;
    }

    u16* Ob = O + (size_t)c * PTOT;
    const int i0 = ti * 128 + (wm << 6);
    const int j0 = tj * 128 + (wn << 6);
#pragma unroll
    for (int mf = 0; mf < 4; ++mf)
#pragma unroll
        for (int nf = 0; nf < 4; ++nf) {
            int jc = j0 + (nf << 4) + (l & 15);
#pragma unroll
            for (int rg = 0; rg < 4; ++rg) {
                int irow = i0 + (mf << 4) + ((l >> 4) << 2) + rg;
                Ob[(size_t)irow * NN + jc] = f2bf(acc[mf][nf][rg]);
            }
        }
}

// ---------------------------------------------------------------------------
// Kernel 3: out[p][co] = z[p][co] + sum_c O[c][p] * Wz[c][co] + b_z[co]
// 128-position tile; O staged transposed [p][c] in swizzled LDS.
// ---------------------------------------------------------------------------
__global__ __launch_bounds__(256) void finalk(
    const u16* __restrict__ O, const u16* __restrict__ Wzt,
    const float* __restrict__ z, const float* __restrict__ bz,
    float* __restrict__ out)
{
    __shared__ u16 Ot[128 * 128];  // [p][c], 16B-unit swizzled

    const int t = threadIdx.x, l = t & 63, w = t >> 6;
    const int p0 = blockIdx.x << 7;

#pragma unroll
    for (int rep = 0; rep < 8; ++rep) {
        int chunk = rep * 256 + t;      // 0..2047
        int c  = chunk >> 4;            // 0..127
        int pc = chunk & 15;            // 8-position chunk
        uint4 vv = *(const uint4*)(O + (size_t)c * PTOT + p0 + (pc << 3));
        const u16* vs = (const u16*)&vv;
#pragma unroll
        for (int e = 0; e < 8; ++e) {
            int p  = (pc << 3) + e;
            int su = (c >> 3) ^ ((p >> 3) & 15) ^ (p & 7);
            Ot[(p << 7) + (su << 3) + (c & 7)] = vs[e];
        }
    }
    __syncthreads();

    f32x4 zero4 = {0.f, 0.f, 0.f, 0.f};
    f32x4 acc[2][8];
#pragma unroll
    for (int mf = 0; mf < 2; ++mf)
#pragma unroll
        for (int nf = 0; nf < 8; ++nf) acc[mf][nf] = zero4;

#pragma unroll
    for (int kk = 0; kk < 4; ++kk) {
        bf16x8 af[2];
#pragma unroll
        for (int mf = 0; mf < 2; ++mf) {
            int p  = (w << 5) + (mf << 4) + (l & 15);
            int su = ((kk << 2) + (l >> 4)) ^ ((p >> 3) & 15) ^ (p & 7);
            af[mf] = *(const bf16x8*)&Ot[(p << 7) + (su << 3)];
        }
#pragma unroll
        for (int nf = 0; nf < 8; ++nf) {
            int co = (nf << 4) + (l & 15);
            bf16x8 bw = *(const bf16x8*)&Wzt[(co << 7) + (kk << 5) + ((l >> 4) << 3)];
#pragma unroll
            for (int mf = 0; mf < 2; ++mf)
                acc[mf][nf] = mfma16(af[mf], bw, acc[mf][nf]);
        }
    }

#pragma unroll
    for (int nf = 0; nf < 8; ++nf) {
        int co = (nf << 4) + (l & 15);
        float b = bz[co];
#pragma unroll
        for (int mf = 0; mf < 2; ++mf) {
#pragma unroll
            for (int rg = 0; rg < 4; ++rg) {
                int p = (w << 5) + (mf << 4) + ((l >> 4) << 2) + rg;
                size_t idx = (size_t)(p0 + p) * CZ + co;
                out[idx] = z[idx] + acc[mf][nf][rg] + b;
            }
        }
    }
}

// ---------------------------------------------------------------------------
extern "C" void kernel_launch(void* const* d_in, const int* in_sizes, int n_in,
                              void* d_out, int out_size, void* d_ws, size_t ws_size,
                              hipStream_t stream)
{
    const float* z    = (const float*)d_in[0];
    const float* mask = (const float*)d_in[1];
    const float* lnw  = (const float*)d_in[2];
    const float* lnb  = (const float*)d_in[3];
    const float* Wap  = (const float*)d_in[4];
    const float* bap  = (const float*)d_in[5];
    const float* Wag  = (const float*)d_in[6];
    const float* bag  = (const float*)d_in[7];
    const float* Wbp  = (const float*)d_in[8];
    const float* bbp  = (const float*)d_in[9];
    const float* Wbg  = (const float*)d_in[10];
    const float* bbg  = (const float*)d_in[11];
    const float* Wz   = (const float*)d_in[12];
    const float* bz   = (const float*)d_in[13];
    float* out = (float*)d_out;

    u16* A_t  = (u16*)d_ws;                       // [128][512][512] bf16, 67 MB
    u16* B_tt = A_t  + (size_t)CZ * PTOT;         // [128][512][512] bf16, 67 MB
    u16* O_t  = B_tt + (size_t)CZ * PTOT;         // [128][512][512] bf16, 67 MB
    u16* Wt   = O_t  + (size_t)CZ * PTOT;         // 5 x [128][128] bf16
    u16* Wzt  = Wt + 4 * 16384;

    prep_w<<<5, 256, 0, stream>>>(Wap, Wag, Wbp, Wbg, Wz, Wt);
    ln_proj<<<dim3(4096, 2), 256, 0, stream>>>(z, mask, lnw, lnb, Wt,
                                               bap, bag, bbp, bbg, A_t, B_tt);
    cgemm<<<2048, 256, 0, stream>>>(A_t, B_tt, O_t);
    finalk<<<2048, 256, 0, stream>>>(O_t, Wzt, z, bz, out);
}

// Round 3
// 600.929 us; speedup vs baseline: 1.0904x; 1.0904x over previous
//
#include <hip/hip_runtime.h>
#include <hip/hip_bf16.h>
#include <cstdint>

#define NN   512
#define CZ   128
#define PTOT (NN * NN)

typedef unsigned short u16;
typedef unsigned int   u32;

using f32x4  = __attribute__((ext_vector_type(4))) float;
using bf16x8 = __attribute__((ext_vector_type(8))) __bf16;

__device__ __forceinline__ u16 f2bf(float x) {
    u32 u = __float_as_uint(x);
    u = (u + 0x7fffu + ((u >> 16) & 1u)) >> 16;
    return (u16)u;
}

__device__ __forceinline__ f32x4 mfma16(bf16x8 a, bf16x8 b, f32x4 c) {
    return __builtin_amdgcn_mfma_f32_16x16x32_bf16(a, b, c, 0, 0, 0);
}

#define GLDS16(src, dst) __builtin_amdgcn_global_load_lds(                  \
        (__attribute__((address_space(1))) void*)(src),                     \
        (__attribute__((address_space(3))) void*)(dst), 16, 0, 0)

// ---------------------------------------------------------------------------
// Kernel 0: weight prep. Wt[m][n][k] = W_m[k][n] as bf16.
// ---------------------------------------------------------------------------
__global__ __launch_bounds__(256) void prep_w(
    const float* __restrict__ w0, const float* __restrict__ w1,
    const float* __restrict__ w2, const float* __restrict__ w3,
    const float* __restrict__ w4, u16* __restrict__ out)
{
    const float* srcs[5] = {w0, w1, w2, w3, w4};
    const float* src = srcs[blockIdx.x];
    u16* dst = out + blockIdx.x * 16384;
    for (int idx = threadIdx.x; idx < 16384; idx += 256) {
        int n = idx >> 7, k = idx & 127;
        dst[idx] = f2bf(src[k * 128 + n]);
    }
}

// ---------------------------------------------------------------------------
// Kernel 1: LayerNorm z -> zn bf16 [p][c]. Memory-bound.
// Block: 256 threads = 64 rows x 4 (32 channels each).
// ---------------------------------------------------------------------------
__global__ __launch_bounds__(256) void ln_k(
    const float* __restrict__ z, const float* __restrict__ lnw,
    const float* __restrict__ lnb, u16* __restrict__ zn)
{
    const int t = threadIdx.x;
    const int r = t >> 2, q = t & 3;
    const long prow = (long)blockIdx.x * 64 + r;
    const float4* zp = (const float4*)(z + prow * CZ + q * 32);

    float v[32];
    float s = 0.f, s2 = 0.f;
#pragma unroll
    for (int j = 0; j < 8; ++j) {
        float4 x = zp[j];
        v[j * 4 + 0] = x.x; v[j * 4 + 1] = x.y;
        v[j * 4 + 2] = x.z; v[j * 4 + 3] = x.w;
        s  += x.x + x.y + x.z + x.w;
        s2 += x.x * x.x + x.y * x.y + x.z * x.z + x.w * x.w;
    }
    s  += __shfl_xor(s, 1);  s  += __shfl_xor(s, 2);
    s2 += __shfl_xor(s2, 1); s2 += __shfl_xor(s2, 2);
    float mu  = s * (1.f / 128.f);
    float var = s2 * (1.f / 128.f) - mu * mu;
    float rs  = rsqrtf(var + 1e-5f);

    const float4* lwp = (const float4*)(lnw + q * 32);
    const float4* lbp = (const float4*)(lnb + q * 32);
    u32 pk[16];
#pragma unroll
    for (int j = 0; j < 8; ++j) {
        float4 lw = lwp[j], lb = lbp[j];
        float a0 = (v[j * 4 + 0] - mu) * rs * lw.x + lb.x;
        float a1 = (v[j * 4 + 1] - mu) * rs * lw.y + lb.y;
        float a2 = (v[j * 4 + 2] - mu) * rs * lw.z + lb.z;
        float a3 = (v[j * 4 + 3] - mu) * rs * lw.w + lb.w;
        pk[j * 2 + 0] = (u32)f2bf(a0) | ((u32)f2bf(a1) << 16);
        pk[j * 2 + 1] = (u32)f2bf(a2) | ((u32)f2bf(a3) << 16);
    }
    uint4* dst = (uint4*)(zn + prow * CZ + q * 32);
#pragma unroll
    for (int j = 0; j < 4; ++j) {
        uint4 w4; w4.x = pk[j*4]; w4.y = pk[j*4+1]; w4.z = pk[j*4+2]; w4.w = pk[j*4+3];
        dst[j] = w4;
    }
}

// ---------------------------------------------------------------------------
// Kernel 2: projection + sigmoid gate + mask, transposed store.
// flavor 0: tile = (i=ir, k=k0..k0+63) -> a -> Aout[c][i][k]
// flavor 1: tile = (k=k0..k0+63, j=ir) -> b -> Bout[c][j][k]
// zn tile staged via global_load_lds with pre-swizzled source addresses.
// ---------------------------------------------------------------------------
__global__ __launch_bounds__(256) void proj_k(
    const u16* __restrict__ zn,   const float* __restrict__ mask,
    const u16* __restrict__ Wt,
    const float* __restrict__ b_ap, const float* __restrict__ b_ag,
    const float* __restrict__ b_bp, const float* __restrict__ b_bg,
    u16* __restrict__ Aout, u16* __restrict__ Bout)
{
    __shared__ u16  znl[64 * 128];   // [row][128 ch], 16B-unit XOR swizzled
    __shared__ u16  tbuf[128 * 72];  // [hid ch][64 rows], stride 72
    __shared__ float lmask[64];

    const int t    = threadIdx.x, l = t & 63, w = t >> 6;
    const int tile = blockIdx.x;
    const int flav = blockIdx.y;
    const int ir   = tile >> 3;
    const int k0   = (tile & 7) << 6;

    // ---- stage zn tile: 4 GLDS16 per wave; LDS unit (row,u) <- zn[row][(u^(row&15))*8..]
    {
        const int u = l & 15;
#pragma unroll
        for (int i = 0; i < 4; ++i) {
            int row = (w << 4) + (i << 2) + (l >> 4);
            long prow = flav ? ((long)(k0 + row) * NN + ir)
                             : ((long)ir * NN + k0 + row);
            const u16* src = zn + prow * CZ + ((u ^ (row & 15)) << 3);
            GLDS16(src, &znl[((w << 4) + (i << 2)) << 7]);
        }
    }
    if (t < 64) {
        long prow = flav ? ((long)(k0 + t) * NN + ir) : ((long)ir * NN + k0 + t);
        lmask[t] = mask[prow];
    }
    __syncthreads();

    // ---- GEMM: M=64 rows x (2 matrices x 32 cols per wave), K=128 ----
    const u16* Wp = Wt + (flav * 2 + 0) * 16384;
    const u16* Wg = Wt + (flav * 2 + 1) * 16384;

    f32x4 zero4 = {0.f, 0.f, 0.f, 0.f};
    f32x4 accP[4][2], accG[4][2];
#pragma unroll
    for (int mf = 0; mf < 4; ++mf)
#pragma unroll
        for (int nf = 0; nf < 2; ++nf) { accP[mf][nf] = zero4; accG[mf][nf] = zero4; }

#pragma unroll
    for (int kk = 0; kk < 4; ++kk) {
        bf16x8 af[4];
#pragma unroll
        for (int mf = 0; mf < 4; ++mf) {
            int row = (mf << 4) + (l & 15);
            int su  = (kk * 4 + (l >> 4)) ^ (row & 15);
            af[mf] = *(const bf16x8*)&znl[(row << 7) + (su << 3)];
        }
#pragma unroll
        for (int nf = 0; nf < 2; ++nf) {
            int n  = (w << 5) + (nf << 4) + (l & 15);
            int ko = (kk << 5) + ((l >> 4) << 3);
            bf16x8 bp = *(const bf16x8*)&Wp[(n << 7) + ko];
            bf16x8 bg = *(const bf16x8*)&Wg[(n << 7) + ko];
#pragma unroll
            for (int mf = 0; mf < 4; ++mf) {
                accP[mf][nf] = mfma16(af[mf], bp, accP[mf][nf]);
                accG[mf][nf] = mfma16(af[mf], bg, accG[mf][nf]);
            }
        }
    }

    // ---- gate + mask, packed transposed write [hid][row] ----
    const float* bPp = flav ? b_bp : b_ap;
    const float* bGp = flav ? b_bg : b_ag;
#pragma unroll
    for (int nf = 0; nf < 2; ++nf) {
        int col = (w << 5) + (nf << 4) + (l & 15);
        float bp = bPp[col], bg = bGp[col];
#pragma unroll
        for (int mf = 0; mf < 4; ++mf) {
            int row0 = (mf << 4) + ((l >> 4) << 2);
            float av[4];
#pragma unroll
            for (int rg = 0; rg < 4; ++rg) {
                float pv = accP[mf][nf][rg] + bp;
                float gv = accG[mf][nf][rg] + bg;
                av[rg] = pv * (1.f / (1.f + __expf(-gv))) * lmask[row0 + rg];
            }
            uint2 packed;
            packed.x = (u32)f2bf(av[0]) | ((u32)f2bf(av[1]) << 16);
            packed.y = (u32)f2bf(av[2]) | ((u32)f2bf(av[3]) << 16);
            *(uint2*)&tbuf[col * 72 + row0] = packed;
        }
    }
    __syncthreads();

    // ---- coalesced store: out[c][ir][k0 + 0..63] ----
    u16* outp = flav ? Bout : Aout;
    const int c = t >> 1, half = t & 1;
    u16* dst = outp + (size_t)c * PTOT + (size_t)ir * NN + k0 + half * 32;
    const u16* srcb = &tbuf[c * 72 + half * 32];
#pragma unroll
    for (int e = 0; e < 4; ++e)
        *(uint4*)(dst + e * 8) = *(const uint4*)(srcb + e * 8);
}

// ---------------------------------------------------------------------------
// Kernel 3: per-channel GEMM  O[c][i][j] = sum_k A[c][i][k] * B[c][j][k]
// 128x128 tile, BK=64, double-buffered global_load_lds, source-side XOR swizzle.
// XCD-chunked block swizzle (T1): each XCD owns 16 complete channels.
// ---------------------------------------------------------------------------
__global__ __launch_bounds__(256) void cgemm(
    const u16* __restrict__ A, const u16* __restrict__ B, u16* __restrict__ O)
{
    __shared__ u16 ldsA[2][128 * 64];
    __shared__ u16 ldsB[2][128 * 64];

    const int t = threadIdx.x, l = t & 63, w = t >> 6;
    // T1: bijective XCD-chunked remap (2048 % 8 == 0)
    const int bx0 = blockIdx.x;
    const int bx  = (bx0 & 7) * 256 + (bx0 >> 3);
    const int c  = bx >> 4, ti = (bx >> 2) & 3, tj = bx & 3;
    const u16* Ab = A + (size_t)c * PTOT + (size_t)(ti * 128) * NN;
    const u16* Bb = B + (size_t)c * PTOT + (size_t)(tj * 128) * NN;

    const int lr8 = (w << 3) + (l >> 3);  // wave-local row within 32-row round
    const int uu  = l & 7;                // 16B unit

    auto stage = [&](int buf, int kt) {
#pragma unroll
        for (int ri = 0; ri < 4; ++ri) {
            int row = ri * 32 + lr8;
            const u16* sa = Ab + (size_t)row * NN + (kt << 6) + ((uu ^ (row & 7)) << 3);
            const u16* sb = Bb + (size_t)row * NN + (kt << 6) + ((uu ^ (row & 7)) << 3);
            u16* da = &ldsA[buf][(ri * 32 + (w << 3)) << 6];
            u16* db = &ldsB[buf][(ri * 32 + (w << 3)) << 6];
            GLDS16(sa, da);
            GLDS16(sb, db);
        }
    };

    const int wm = w >> 1, wn = w & 1;
    f32x4 zero4 = {0.f, 0.f, 0.f, 0.f};
    f32x4 acc[4][4];
#pragma unroll
    for (int mf = 0; mf < 4; ++mf)
#pragma unroll
        for (int nf = 0; nf < 4; ++nf) acc[mf][nf] = zero4;

    stage(0, 0);
    __syncthreads();
    int cur = 0;
    for (int kt = 0; kt < 8; ++kt) {
        if (kt < 7) stage(cur ^ 1, kt + 1);
        const u16* lA = ldsA[cur];
        const u16* lB = ldsB[cur];
#pragma unroll
        for (int kk = 0; kk < 2; ++kk) {
            bf16x8 af[4], bfr[4];
#pragma unroll
            for (int mf = 0; mf < 4; ++mf) {
                int row = (wm << 6) + (mf << 4) + (l & 15);
                int su  = ((kk << 2) + (l >> 4)) ^ (row & 7);
                af[mf] = *(const bf16x8*)&lA[(row << 6) + (su << 3)];
            }
#pragma unroll
            for (int nf = 0; nf < 4; ++nf) {
                int row = (wn << 6) + (nf << 4) + (l & 15);
                int su  = ((kk << 2) + (l >> 4)) ^ (row & 7);
                bfr[nf] = *(const bf16x8*)&lB[(row << 6) + (su << 3)];
            }
#pragma unroll
            for (int mf = 0; mf < 4; ++mf)
#pragma unroll
                for (int nf = 0; nf < 4; ++nf)
                    acc[mf][nf] = mfma16(af[mf], bfr[nf], acc[mf][nf]);
        }
        if (kt < 7) __syncthreads();
        cur ^= 1;
    }

    u16* Ob = O + (size_t)c * PTOT;
    const int i0 = ti * 128 + (wm << 6);
    const int j0 = tj * 128 + (wn << 6);
#pragma unroll
    for (int mf = 0; mf < 4; ++mf)
#pragma unroll
        for (int nf = 0; nf < 4; ++nf) {
            int jc = j0 + (nf << 4) + (l & 15);
#pragma unroll
            for (int rg = 0; rg < 4; ++rg) {
                int irow = i0 + (mf << 4) + ((l >> 4) << 2) + rg;
                Ob[(size_t)irow * NN + jc] = f2bf(acc[mf][nf][rg]);
            }
        }
}

// ---------------------------------------------------------------------------
// Kernel 4: out[p][co] = z[p][co] + sum_c O[c][p] * Wz[c][co] + b_z[co]
// ---------------------------------------------------------------------------
__global__ __launch_bounds__(256) void finalk(
    const u16* __restrict__ O, const u16* __restrict__ Wzt,
    const float* __restrict__ z, const float* __restrict__ bz,
    float* __restrict__ out)
{
    __shared__ u16 Ot[128 * 128];  // [p][c], 16B-unit swizzled

    const int t = threadIdx.x, l = t & 63, w = t >> 6;
    const int p0 = blockIdx.x << 7;

#pragma unroll
    for (int rep = 0; rep < 8; ++rep) {
        int chunk = rep * 256 + t;      // 0..2047
        int c  = chunk >> 4;            // 0..127
        int pc = chunk & 15;            // 8-position chunk
        uint4 vv = *(const uint4*)(O + (size_t)c * PTOT + p0 + (pc << 3));
        const u16* vs = (const u16*)&vv;
#pragma unroll
        for (int e = 0; e < 8; ++e) {
            int p  = (pc << 3) + e;
            int su = (c >> 3) ^ ((p >> 3) & 15) ^ (p & 7);
            Ot[(p << 7) + (su << 3) + (c & 7)] = vs[e];
        }
    }
    __syncthreads();

    f32x4 zero4 = {0.f, 0.f, 0.f, 0.f};
    f32x4 acc[2][8];
#pragma unroll
    for (int mf = 0; mf < 2; ++mf)
#pragma unroll
        for (int nf = 0; nf < 8; ++nf) acc[mf][nf] = zero4;

#pragma unroll
    for (int kk = 0; kk < 4; ++kk) {
        bf16x8 af[2];
#pragma unroll
        for (int mf = 0; mf < 2; ++mf) {
            int p  = (w << 5) + (mf << 4) + (l & 15);
            int su = ((kk << 2) + (l >> 4)) ^ ((p >> 3) & 15) ^ (p & 7);
            af[mf] = *(const bf16x8*)&Ot[(p << 7) + (su << 3)];
        }
#pragma unroll
        for (int nf = 0; nf < 8; ++nf) {
            int co = (nf << 4) + (l & 15);
            bf16x8 bw = *(const bf16x8*)&Wzt[(co << 7) + (kk << 5) + ((l >> 4) << 3)];
#pragma unroll
            for (int mf = 0; mf < 2; ++mf)
                acc[mf][nf] = mfma16(af[mf], bw, acc[mf][nf]);
        }
    }

#pragma unroll
    for (int nf = 0; nf < 8; ++nf) {
        int co = (nf << 4) + (l & 15);
        float b = bz[co];
#pragma unroll
        for (int mf = 0; mf < 2; ++mf) {
#pragma unroll
            for (int rg = 0; rg < 4; ++rg) {
                int p = (w << 5) + (mf << 4) + ((l >> 4) << 2) + rg;
                size_t idx = (size_t)(p0 + p) * CZ + co;
                out[idx] = z[idx] + acc[mf][nf][rg] + b;
            }
        }
    }
}

// ---------------------------------------------------------------------------
extern "C" void kernel_launch(void* const* d_in, const int* in_sizes, int n_in,
                              void* d_out, int out_size, void* d_ws, size_t ws_size,
                              hipStream_t stream)
{
    const float* z    = (const float*)d_in[0];
    const float* mask = (const float*)d_in[1];
    const float* lnw  = (const float*)d_in[2];
    const float* lnb  = (const float*)d_in[3];
    const float* Wap  = (const float*)d_in[4];
    const float* bap  = (const float*)d_in[5];
    const float* Wag  = (const float*)d_in[6];
    const float* bag  = (const float*)d_in[7];
    const float* Wbp  = (const float*)d_in[8];
    const float* bbp  = (const float*)d_in[9];
    const float* Wbg  = (const float*)d_in[10];
    const float* bbg  = (const float*)d_in[11];
    const float* Wz   = (const float*)d_in[12];
    const float* bz   = (const float*)d_in[13];
    float* out = (float*)d_out;

    u16* A_t  = (u16*)d_ws;                       // [128][512][512] bf16, 67 MB
    u16* B_tt = A_t  + (size_t)CZ * PTOT;         // [128][512][512] bf16, 67 MB
    u16* O_t  = B_tt + (size_t)CZ * PTOT;         // [128][512][512] bf16, 67 MB
    u16* Wt   = O_t  + (size_t)CZ * PTOT;         // 5 x [128][128] bf16
    u16* Wzt  = Wt + 4 * 16384;
    u16* zn   = O_t;  // alias: zn dead before cgemm writes O_t

    prep_w<<<5, 256, 0, stream>>>(Wap, Wag, Wbp, Wbg, Wz, Wt);
    ln_k<<<4096, 256, 0, stream>>>(z, lnw, lnb, zn);
    proj_k<<<dim3(4096, 2), 256, 0, stream>>>(zn, mask, Wt,
                                              bap, bag, bbp, bbg, A_t, B_tt);
    cgemm<<<2048, 256, 0, stream>>>(A_t, B_tt, O_t);
    finalk<<<2048, 256, 0, stream>>>(O_t, Wzt, z, bz, out);
}

// Round 7
// 536.810 us; speedup vs baseline: 1.2207x; 1.1194x over previous
//
#include <hip/hip_runtime.h>
#include <hip/hip_bf16.h>
#include <cstdint>

#define NN   512
#define CZ   128
#define PTOT (NN * NN)

typedef unsigned short u16;
typedef unsigned int   u32;

using f32x4  = __attribute__((ext_vector_type(4))) float;
using bf16x8 = __attribute__((ext_vector_type(8))) __bf16;

__device__ __forceinline__ u16 f2bf(float x) {
    u32 u = __float_as_uint(x);
    u = (u + 0x7fffu + ((u >> 16) & 1u)) >> 16;
    return (u16)u;
}

__device__ __forceinline__ f32x4 mfma16(bf16x8 a, bf16x8 b, f32x4 c) {
    return __builtin_amdgcn_mfma_f32_16x16x32_bf16(a, b, c, 0, 0, 0);
}

#define GLDS16(src, dst) __builtin_amdgcn_global_load_lds(                  \
        (__attribute__((address_space(1))) void*)(src),                     \
        (__attribute__((address_space(3))) void*)(dst), 16, 0, 0)

// ---------------------------------------------------------------------------
// Kernel 0: weight prep. Wt[m][n][k] = W_m[k][n] as bf16.
// ---------------------------------------------------------------------------
__global__ __launch_bounds__(256) void prep_w(
    const float* __restrict__ w0, const float* __restrict__ w1,
    const float* __restrict__ w2, const float* __restrict__ w3,
    const float* __restrict__ w4, u16* __restrict__ out)
{
    const float* srcs[5] = {w0, w1, w2, w3, w4};
    const float* src = srcs[blockIdx.x];
    u16* dst = out + blockIdx.x * 16384;
    for (int idx = threadIdx.x; idx < 16384; idx += 256) {
        int n = idx >> 7, k = idx & 127;
        dst[idx] = f2bf(src[k * 128 + n]);
    }
}

// ---------------------------------------------------------------------------
// Kernel 1: LayerNorm z -> zn bf16 [p][c]. Memory-bound.
// ---------------------------------------------------------------------------
__global__ __launch_bounds__(256) void ln_k(
    const float* __restrict__ z, const float* __restrict__ lnw,
    const float* __restrict__ lnb, u16* __restrict__ zn)
{
    const int t = threadIdx.x;
    const int r = t >> 2, q = t & 3;
    const long prow = (long)blockIdx.x * 64 + r;
    const float4* zp = (const float4*)(z + prow * CZ + q * 32);

    float v[32];
    float s = 0.f, s2 = 0.f;
#pragma unroll
    for (int j = 0; j < 8; ++j) {
        float4 x = zp[j];
        v[j * 4 + 0] = x.x; v[j * 4 + 1] = x.y;
        v[j * 4 + 2] = x.z; v[j * 4 + 3] = x.w;
        s  += x.x + x.y + x.z + x.w;
        s2 += x.x * x.x + x.y * x.y + x.z * x.z + x.w * x.w;
    }
    s  += __shfl_xor(s, 1);  s  += __shfl_xor(s, 2);
    s2 += __shfl_xor(s2, 1); s2 += __shfl_xor(s2, 2);
    float mu  = s * (1.f / 128.f);
    float var = s2 * (1.f / 128.f) - mu * mu;
    float rs  = rsqrtf(var + 1e-5f);

    const float4* lwp = (const float4*)(lnw + q * 32);
    const float4* lbp = (const float4*)(lnb + q * 32);
    u32 pk[16];
#pragma unroll
    for (int j = 0; j < 8; ++j) {
        float4 lw = lwp[j], lb = lbp[j];
        float a0 = (v[j * 4 + 0] - mu) * rs * lw.x + lb.x;
        float a1 = (v[j * 4 + 1] - mu) * rs * lw.y + lb.y;
        float a2 = (v[j * 4 + 2] - mu) * rs * lw.z + lb.z;
        float a3 = (v[j * 4 + 3] - mu) * rs * lw.w + lb.w;
        pk[j * 2 + 0] = (u32)f2bf(a0) | ((u32)f2bf(a1) << 16);
        pk[j * 2 + 1] = (u32)f2bf(a2) | ((u32)f2bf(a3) << 16);
    }
    uint4* dst = (uint4*)(zn + prow * CZ + q * 32);
#pragma unroll
    for (int j = 0; j < 4; ++j) {
        uint4 w4; w4.x = pk[j*4]; w4.y = pk[j*4+1]; w4.z = pk[j*4+2]; w4.w = pk[j*4+3];
        dst[j] = w4;
    }
}

// ---------------------------------------------------------------------------
// Kernel 2: projection + sigmoid gate + mask, transposed store.
// ---------------------------------------------------------------------------
__global__ __launch_bounds__(256) void proj_k(
    const u16* __restrict__ zn,   const float* __restrict__ mask,
    const u16* __restrict__ Wt,
    const float* __restrict__ b_ap, const float* __restrict__ b_ag,
    const float* __restrict__ b_bp, const float* __restrict__ b_bg,
    u16* __restrict__ Aout, u16* __restrict__ Bout)
{
    __shared__ u16  znl[64 * 128];   // [row][128 ch], 16B-unit XOR swizzled
    __shared__ u16  tbuf[128 * 72];  // [hid ch][64 rows], stride 72
    __shared__ float lmask[64];

    const int t    = threadIdx.x, l = t & 63, w = t >> 6;
    const int tile = blockIdx.x;
    const int flav = blockIdx.y;
    const int ir   = tile >> 3;
    const int k0   = (tile & 7) << 6;

    {
        const int u = l & 15;
#pragma unroll
        for (int i = 0; i < 4; ++i) {
            int row = (w << 4) + (i << 2) + (l >> 4);
            long prow = flav ? ((long)(k0 + row) * NN + ir)
                             : ((long)ir * NN + k0 + row);
            const u16* src = zn + prow * CZ + ((u ^ (row & 15)) << 3);
            GLDS16(src, &znl[((w << 4) + (i << 2)) << 7]);
        }
    }
    if (t < 64) {
        long prow = flav ? ((long)(k0 + t) * NN + ir) : ((long)ir * NN + k0 + t);
        lmask[t] = mask[prow];
    }
    __syncthreads();

    const u16* Wp = Wt + (flav * 2 + 0) * 16384;
    const u16* Wg = Wt + (flav * 2 + 1) * 16384;

    f32x4 zero4 = {0.f, 0.f, 0.f, 0.f};
    f32x4 accP[4][2], accG[4][2];
#pragma unroll
    for (int mf = 0; mf < 4; ++mf)
#pragma unroll
        for (int nf = 0; nf < 2; ++nf) { accP[mf][nf] = zero4; accG[mf][nf] = zero4; }

#pragma unroll
    for (int kk = 0; kk < 4; ++kk) {
        bf16x8 af[4];
#pragma unroll
        for (int mf = 0; mf < 4; ++mf) {
            int row = (mf << 4) + (l & 15);
            int su  = (kk * 4 + (l >> 4)) ^ (row & 15);
            af[mf] = *(const bf16x8*)&znl[(row << 7) + (su << 3)];
        }
#pragma unroll
        for (int nf = 0; nf < 2; ++nf) {
            int n  = (w << 5) + (nf << 4) + (l & 15);
            int ko = (kk << 5) + ((l >> 4) << 3);
            bf16x8 bp = *(const bf16x8*)&Wp[(n << 7) + ko];
            bf16x8 bg = *(const bf16x8*)&Wg[(n << 7) + ko];
#pragma unroll
            for (int mf = 0; mf < 4; ++mf) {
                accP[mf][nf] = mfma16(af[mf], bp, accP[mf][nf]);
                accG[mf][nf] = mfma16(af[mf], bg, accG[mf][nf]);
            }
        }
    }

    const float* bPp = flav ? b_bp : b_ap;
    const float* bGp = flav ? b_bg : b_ag;
#pragma unroll
    for (int nf = 0; nf < 2; ++nf) {
        int col = (w << 5) + (nf << 4) + (l & 15);
        float bp = bPp[col], bg = bGp[col];
#pragma unroll
        for (int mf = 0; mf < 4; ++mf) {
            int row0 = (mf << 4) + ((l >> 4) << 2);
            float av[4];
#pragma unroll
            for (int rg = 0; rg < 4; ++rg) {
                float pv = accP[mf][nf][rg] + bp;
                float gv = accG[mf][nf][rg] + bg;
                av[rg] = pv * (1.f / (1.f + __expf(-gv))) * lmask[row0 + rg];
            }
            uint2 packed;
            packed.x = (u32)f2bf(av[0]) | ((u32)f2bf(av[1]) << 16);
            packed.y = (u32)f2bf(av[2]) | ((u32)f2bf(av[3]) << 16);
            *(uint2*)&tbuf[col * 72 + row0] = packed;
        }
    }
    __syncthreads();

    u16* outp = flav ? Bout : Aout;
    const int c = t >> 1, half = t & 1;
    u16* dst = outp + (size_t)c * PTOT + (size_t)ir * NN + k0 + half * 32;
    const u16* srcb = &tbuf[c * 72 + half * 32];
#pragma unroll
    for (int e = 0; e < 4; ++e)
        *(uint4*)(dst + e * 8) = *(const uint4*)(srcb + e * 8);
}

// ---------------------------------------------------------------------------
// Kernel 3: per-channel GEMM  O[c][i][j] = sum_k A[c][i][k] * B[c][j][k]
// ---------------------------------------------------------------------------
__global__ __launch_bounds__(256) void cgemm(
    const u16* __restrict__ A, const u16* __restrict__ B, u16* __restrict__ O)
{
    __shared__ u16 ldsA[2][128 * 64];
    __shared__ u16 ldsB[2][128 * 64];

    const int t = threadIdx.x, l = t & 63, w = t >> 6;
    const int bx0 = blockIdx.x;
    const int bx  = (bx0 & 7) * 256 + (bx0 >> 3);
    const int c  = bx >> 4, ti = (bx >> 2) & 3, tj = bx & 3;
    const u16* Ab = A + (size_t)c * PTOT + (size_t)(ti * 128) * NN;
    const u16* Bb = B + (size_t)c * PTOT + (size_t)(tj * 128) * NN;

    const int lr8 = (w << 3) + (l >> 3);
    const int uu  = l & 7;

    auto stage = [&](int buf, int kt) {
#pragma unroll
        for (int ri = 0; ri < 4; ++ri) {
            int row = ri * 32 + lr8;
            const u16* sa = Ab + (size_t)row * NN + (kt << 6) + ((uu ^ (row & 7)) << 3);
            const u16* sb = Bb + (size_t)row * NN + (kt << 6) + ((uu ^ (row & 7)) << 3);
            u16* da = &ldsA[buf][(ri * 32 + (w << 3)) << 6];
            u16* db = &ldsB[buf][(ri * 32 + (w << 3)) << 6];
            GLDS16(sa, da);
            GLDS16(sb, db);
        }
    };

    const int wm = w >> 1, wn = w & 1;
    f32x4 zero4 = {0.f, 0.f, 0.f, 0.f};
    f32x4 acc[4][4];
#pragma unroll
    for (int mf = 0; mf < 4; ++mf)
#pragma unroll
        for (int nf = 0; nf < 4; ++nf) acc[mf][nf] = zero4;

    stage(0, 0);
    __syncthreads();
    int cur = 0;
    for (int kt = 0; kt < 8; ++kt) {
        if (kt < 7) stage(cur ^ 1, kt + 1);
        const u16* lA = ldsA[cur];
        const u16* lB = ldsB[cur];
#pragma unroll
        for (int kk = 0; kk < 2; ++kk) {
            bf16x8 af[4], bfr[4];
#pragma unroll
            for (int mf = 0; mf < 4; ++mf) {
                int row = (wm << 6) + (mf << 4) + (l & 15);
                int su  = ((kk << 2) + (l >> 4)) ^ (row & 7);
                af[mf] = *(const bf16x8*)&lA[(row << 6) + (su << 3)];
            }
#pragma unroll
            for (int nf = 0; nf < 4; ++nf) {
                int row = (wn << 6) + (nf << 4) + (l & 15);
                int su  = ((kk << 2) + (l >> 4)) ^ (row & 7);
                bfr[nf] = *(const bf16x8*)&lB[(row << 6) + (su << 3)];
            }
#pragma unroll
            for (int mf = 0; mf < 4; ++mf)
#pragma unroll
                for (int nf = 0; nf < 4; ++nf)
                    acc[mf][nf] = mfma16(af[mf], bfr[nf], acc[mf][nf]);
        }
        if (kt < 7) __syncthreads();
        cur ^= 1;
    }

    u16* Ob = O + (size_t)c * PTOT;
    const int i0 = ti * 128 + (wm << 6);
    const int j0 = tj * 128 + (wn << 6);
#pragma unroll
    for (int mf = 0; mf < 4; ++mf)
#pragma unroll
        for (int nf = 0; nf < 4; ++nf) {
            int jc = j0 + (nf << 4) + (l & 15);
#pragma unroll
            for (int rg = 0; rg < 4; ++rg) {
                int irow = i0 + (mf << 4) + ((l >> 4) << 2) + rg;
                Ob[(size_t)irow * NN + jc] = f2bf(acc[mf][nf][rg]);
            }
        }
}

// ---------------------------------------------------------------------------
// Kernel 4: out[p][co] = z[p][co] + sum_c O[c][p]*Wz[c][co] + b_z[co]
// Swapped MFMA roles: D[row=co][col=p] via A=Wzt[co][c], B=Ot[p][c].
// -> each lane owns 4 consecutive co => float4 z-loads and out-stores.
// Transpose staging fully vectorized: 8x uint4 load + reg transpose + 8x b128.
// Swizzle: unit uc of row p stored at slot su = uc ^ (p&15) ^ ((p>>4)&7).
// ---------------------------------------------------------------------------
__global__ __launch_bounds__(256) void finalk(
    const u16* __restrict__ O, const u16* __restrict__ Wzt,
    const float* __restrict__ z, const float* __restrict__ bz,
    float* __restrict__ out)
{
    __shared__ u16 Ot[128 * 128];  // [p][c], swizzled

    const int t = threadIdx.x, l = t & 63, w = t >> 6;
    const int p0 = blockIdx.x << 7;

    // ---- phase 1: transpose O[c][p-tile] -> Ot[p][c] ----
    {
        const int po = t & 15;        // p-octet: p = po*8 .. +7
        const int uc = t >> 4;        // c-octet index 0..15, c0 = uc*8
        uint4 q[8];
#pragma unroll
        for (int cc = 0; cc < 8; ++cc)
            q[cc] = *(const uint4*)(O + (size_t)(uc * 8 + cc) * PTOT + p0 + po * 8);
#pragma unroll
        for (int e = 0; e < 8; ++e) {
            const int sh = (e & 1) * 16;
            const int wd = e >> 1;
            u32 h[8];
#pragma unroll
            for (int cc = 0; cc < 8; ++cc)
                h[cc] = (((const u32*)&q[cc])[wd] >> sh) & 0xffffu;
            uint4 o;
            o.x = h[0] | (h[1] << 16);
            o.y = h[2] | (h[3] << 16);
            o.z = h[4] | (h[5] << 16);
            o.w = h[6] | (h[7] << 16);
            int p  = po * 8 + e;
            int su = uc ^ (p & 15) ^ ((p >> 4) & 7);
            *(uint4*)&Ot[(p << 7) + (su << 3)] = o;
        }
    }
    __syncthreads();

    // ---- phase 2: MFMA. Wave w owns p-range [w*32, w*32+32). ----
    f32x4 zero4 = {0.f, 0.f, 0.f, 0.f};
    f32x4 acc[8][2];   // [mco][np]
#pragma unroll
    for (int m = 0; m < 8; ++m)
#pragma unroll
        for (int np = 0; np < 2; ++np) acc[m][np] = zero4;

#pragma unroll
    for (int kk = 0; kk < 4; ++kk) {
        bf16x8 af[8];
#pragma unroll
        for (int m = 0; m < 8; ++m) {
            int co = (m << 4) + (l & 15);
            af[m] = *(const bf16x8*)&Wzt[(co << 7) + (kk << 5) + ((l >> 4) << 3)];
        }
#pragma unroll
        for (int np = 0; np < 2; ++np) {
            int p  = (w << 5) + (np << 4) + (l & 15);
            int su = ((kk << 2) + (l >> 4)) ^ (p & 15) ^ ((p >> 4) & 7);
            bf16x8 bfr = *(const bf16x8*)&Ot[(p << 7) + (su << 3)];
#pragma unroll
            for (int m = 0; m < 8; ++m)
                acc[m][np] = mfma16(af[m], bfr, acc[m][np]);
        }
    }

    // ---- epilogue: float4 z-load + add + float4 store ----
#pragma unroll
    for (int m = 0; m < 8; ++m) {
        const int co4 = (m << 4) + ((l >> 4) << 2);
        const float4 bv = *(const float4*)&bz[co4];
#pragma unroll
        for (int np = 0; np < 2; ++np) {
            int p = p0 + (w << 5) + (np << 4) + (l & 15);
            size_t idx = (size_t)p * CZ + co4;
            float4 zv = *(const float4*)&z[idx];
            float4 ov;
            ov.x = zv.x + acc[m][np][0] + bv.x;
            ov.y = zv.y + acc[m][np][1] + bv.y;
            ov.z = zv.z + acc[m][np][2] + bv.z;
            ov.w = zv.w + acc[m][np][3] + bv.w;
            *(float4*)&out[idx] = ov;
        }
    }
}

// ---------------------------------------------------------------------------
extern "C" void kernel_launch(void* const* d_in, const int* in_sizes, int n_in,
                              void* d_out, int out_size, void* d_ws, size_t ws_size,
                              hipStream_t stream)
{
    const float* z    = (const float*)d_in[0];
    const float* mask = (const float*)d_in[1];
    const float* lnw  = (const float*)d_in[2];
    const float* lnb  = (const float*)d_in[3];
    const float* Wap  = (const float*)d_in[4];
    const float* bap  = (const float*)d_in[5];
    const float* Wag  = (const float*)d_in[6];
    const float* bag  = (const float*)d_in[7];
    const float* Wbp  = (const float*)d_in[8];
    const float* bbp  = (const float*)d_in[9];
    const float* Wbg  = (const float*)d_in[10];
    const float* bbg  = (const float*)d_in[11];
    const float* Wz   = (const float*)d_in[12];
    const float* bz   = (const float*)d_in[13];
    float* out = (float*)d_out;

    u16* A_t  = (u16*)d_ws;                       // [128][512][512] bf16, 67 MB
    u16* B_tt = A_t  + (size_t)CZ * PTOT;         // 67 MB
    u16* O_t  = B_tt + (size_t)CZ * PTOT;         // 67 MB
    u16* Wt   = O_t  + (size_t)CZ * PTOT;         // 5 x [128][128] bf16
    u16* Wzt  = Wt + 4 * 16384;
    u16* zn   = O_t;  // alias: zn dead before cgemm writes O_t

    prep_w<<<5, 256, 0, stream>>>(Wap, Wag, Wbp, Wbg, Wz, Wt);
    ln_k<<<4096, 256, 0, stream>>>(z, lnw, lnb, zn);
    proj_k<<<dim3(4096, 2), 256, 0, stream>>>(zn, mask, Wt,
                                              bap, bag, bbp, bbg, A_t, B_tt);
    cgemm<<<2048, 256, 0, stream>>>(A_t, B_tt, O_t);
    finalk<<<2048, 256, 0, stream>>>(O_t, Wzt, z, bz, out);
}

// Round 8
// 506.023 us; speedup vs baseline: 1.2950x; 1.0608x over previous
//
#include <hip/hip_runtime.h>
#include <hip/hip_bf16.h>
#include <cstdint>

#define NN   512
#define CZ   128
#define PTOT (NN * NN)

typedef unsigned short u16;
typedef unsigned int   u32;

using f32x4  = __attribute__((ext_vector_type(4))) float;
using bf16x8 = __attribute__((ext_vector_type(8))) __bf16;

__device__ __forceinline__ u16 f2bf(float x) {
    u32 u = __float_as_uint(x);
    u = (u + 0x7fffu + ((u >> 16) & 1u)) >> 16;
    return (u16)u;
}

__device__ __forceinline__ f32x4 mfma16(bf16x8 a, bf16x8 b, f32x4 c) {
    return __builtin_amdgcn_mfma_f32_16x16x32_bf16(a, b, c, 0, 0, 0);
}

#define GLDS16(src, dst) __builtin_amdgcn_global_load_lds(                  \
        (__attribute__((address_space(1))) void*)(src),                     \
        (__attribute__((address_space(3))) void*)(dst), 16, 0, 0)

// ---------------------------------------------------------------------------
// Kernel 0: weight prep. Wt[m][n][k] = W_m[k][n] as bf16.
// ---------------------------------------------------------------------------
__global__ __launch_bounds__(256) void prep_w(
    const float* __restrict__ w0, const float* __restrict__ w1,
    const float* __restrict__ w2, const float* __restrict__ w3,
    const float* __restrict__ w4, u16* __restrict__ out)
{
    const float* srcs[5] = {w0, w1, w2, w3, w4};
    const float* src = srcs[blockIdx.x];
    u16* dst = out + blockIdx.x * 16384;
    for (int idx = threadIdx.x; idx < 16384; idx += 256) {
        int n = idx >> 7, k = idx & 127;
        dst[idx] = f2bf(src[k * 128 + n]);
    }
}

// ---------------------------------------------------------------------------
// Kernel 1: LayerNorm z -> zn bf16 [p][c]. Memory-bound.
// ---------------------------------------------------------------------------
__global__ __launch_bounds__(256) void ln_k(
    const float* __restrict__ z, const float* __restrict__ lnw,
    const float* __restrict__ lnb, u16* __restrict__ zn)
{
    const int t = threadIdx.x;
    const int r = t >> 2, q = t & 3;
    const long prow = (long)blockIdx.x * 64 + r;
    const float4* zp = (const float4*)(z + prow * CZ + q * 32);

    float v[32];
    float s = 0.f, s2 = 0.f;
#pragma unroll
    for (int j = 0; j < 8; ++j) {
        float4 x = zp[j];
        v[j * 4 + 0] = x.x; v[j * 4 + 1] = x.y;
        v[j * 4 + 2] = x.z; v[j * 4 + 3] = x.w;
        s  += x.x + x.y + x.z + x.w;
        s2 += x.x * x.x + x.y * x.y + x.z * x.z + x.w * x.w;
    }
    s  += __shfl_xor(s, 1);  s  += __shfl_xor(s, 2);
    s2 += __shfl_xor(s2, 1); s2 += __shfl_xor(s2, 2);
    float mu  = s * (1.f / 128.f);
    float var = s2 * (1.f / 128.f) - mu * mu;
    float rs  = rsqrtf(var + 1e-5f);

    const float4* lwp = (const float4*)(lnw + q * 32);
    const float4* lbp = (const float4*)(lnb + q * 32);
    u32 pk[16];
#pragma unroll
    for (int j = 0; j < 8; ++j) {
        float4 lw = lwp[j], lb = lbp[j];
        float a0 = (v[j * 4 + 0] - mu) * rs * lw.x + lb.x;
        float a1 = (v[j * 4 + 1] - mu) * rs * lw.y + lb.y;
        float a2 = (v[j * 4 + 2] - mu) * rs * lw.z + lb.z;
        float a3 = (v[j * 4 + 3] - mu) * rs * lw.w + lb.w;
        pk[j * 2 + 0] = (u32)f2bf(a0) | ((u32)f2bf(a1) << 16);
        pk[j * 2 + 1] = (u32)f2bf(a2) | ((u32)f2bf(a3) << 16);
    }
    uint4* dst = (uint4*)(zn + prow * CZ + q * 32);
#pragma unroll
    for (int j = 0; j < 4; ++j) {
        uint4 w4; w4.x = pk[j*4]; w4.y = pk[j*4+1]; w4.z = pk[j*4+2]; w4.w = pk[j*4+3];
        dst[j] = w4;
    }
}

// ---------------------------------------------------------------------------
// Kernel 2 (PIPELINED): projection + sigmoid gate + mask, transposed store.
// Each block processes 4 (tile,flavor) units with double-buffered znl:
// stage(next) GLDS issued right after loop-top sync, overlapping the
// current unit's MFMA+epilogue+store (hides L3/HBM latency).
// unit uid in [0,8192): flav = uid>>12, tile = uid&4095, ir=tile>>3, k0=(tile&7)*64.
// ---------------------------------------------------------------------------
__global__ __launch_bounds__(256) void proj_k(
    const u16* __restrict__ zn,   const float* __restrict__ mask,
    const u16* __restrict__ Wt,
    const float* __restrict__ b_ap, const float* __restrict__ b_ag,
    const float* __restrict__ b_bp, const float* __restrict__ b_bg,
    u16* __restrict__ Aout, u16* __restrict__ Bout)
{
    __shared__ u16  znl[2][64 * 128];  // [buf][row][128 ch], 16B-unit XOR swizzled
    __shared__ u16  tbuf[128 * 72];    // [hid ch][64 rows], stride 72
    __shared__ float lmask[2][64];

    const int t = threadIdx.x, l = t & 63, w = t >> 6;

    // XCD-chunked bijective remap (2048 % 8 == 0): contiguous units per XCD.
    const int bx  = (blockIdx.x & 7) * 256 + (blockIdx.x >> 3);
    const int uid0 = bx * 4;

    auto stageU = [&](int buf, int uid) {
        const int flav = uid >> 12, tile = uid & 4095;
        const int ir = tile >> 3, k0 = (tile & 7) << 6;
        const int u = l & 15;
#pragma unroll
        for (int i = 0; i < 4; ++i) {
            int row = (w << 4) + (i << 2) + (l >> 4);
            long prow = flav ? ((long)(k0 + row) * NN + ir)
                             : ((long)ir * NN + k0 + row);
            const u16* src = zn + prow * CZ + ((u ^ (row & 15)) << 3);
            GLDS16(src, &znl[buf][((w << 4) + (i << 2)) << 7]);
        }
    };
    auto maskU = [&](int buf, int uid) {
        if (t < 64) {
            const int flav = uid >> 12, tile = uid & 4095;
            const int ir = tile >> 3, k0 = (tile & 7) << 6;
            long prow = flav ? ((long)(k0 + t) * NN + ir) : ((long)ir * NN + k0 + t);
            lmask[buf][t] = mask[prow];
        }
    };

    stageU(0, uid0);
    maskU(0, uid0);

    int cur = 0;
    for (int i = 0; i < 4; ++i) {
        const int uid  = uid0 + i;
        const int flav = uid >> 12, tile = uid & 4095;
        const int ir   = tile >> 3, k0 = (tile & 7) << 6;

        __syncthreads();   // drains vmcnt: znl[cur]+lmask[cur] ready; tbuf free

        if (i < 3) { stageU(cur ^ 1, uid + 1); maskU(cur ^ 1, uid + 1); }

        const u16* Wp = Wt + (flav * 2 + 0) * 16384;
        const u16* Wg = Wt + (flav * 2 + 1) * 16384;

        f32x4 zero4 = {0.f, 0.f, 0.f, 0.f};
        f32x4 accP[4][2], accG[4][2];
#pragma unroll
        for (int mf = 0; mf < 4; ++mf)
#pragma unroll
            for (int nf = 0; nf < 2; ++nf) { accP[mf][nf] = zero4; accG[mf][nf] = zero4; }

#pragma unroll
        for (int kk = 0; kk < 4; ++kk) {
            bf16x8 af[4];
#pragma unroll
            for (int mf = 0; mf < 4; ++mf) {
                int row = (mf << 4) + (l & 15);
                int su  = (kk * 4 + (l >> 4)) ^ (row & 15);
                af[mf] = *(const bf16x8*)&znl[cur][(row << 7) + (su << 3)];
            }
#pragma unroll
            for (int nf = 0; nf < 2; ++nf) {
                int n  = (w << 5) + (nf << 4) + (l & 15);
                int ko = (kk << 5) + ((l >> 4) << 3);
                bf16x8 bp = *(const bf16x8*)&Wp[(n << 7) + ko];
                bf16x8 bg = *(const bf16x8*)&Wg[(n << 7) + ko];
#pragma unroll
                for (int mf = 0; mf < 4; ++mf) {
                    accP[mf][nf] = mfma16(af[mf], bp, accP[mf][nf]);
                    accG[mf][nf] = mfma16(af[mf], bg, accG[mf][nf]);
                }
            }
        }

        const float* bPp = flav ? b_bp : b_ap;
        const float* bGp = flav ? b_bg : b_ag;
#pragma unroll
        for (int nf = 0; nf < 2; ++nf) {
            int col = (w << 5) + (nf << 4) + (l & 15);
            float bp = bPp[col], bg = bGp[col];
#pragma unroll
            for (int mf = 0; mf < 4; ++mf) {
                int row0 = (mf << 4) + ((l >> 4) << 2);
                float av[4];
#pragma unroll
                for (int rg = 0; rg < 4; ++rg) {
                    float pv = accP[mf][nf][rg] + bp;
                    float gv = accG[mf][nf][rg] + bg;
                    av[rg] = pv * (1.f / (1.f + __expf(-gv))) * lmask[cur][row0 + rg];
                }
                uint2 packed;
                packed.x = (u32)f2bf(av[0]) | ((u32)f2bf(av[1]) << 16);
                packed.y = (u32)f2bf(av[2]) | ((u32)f2bf(av[3]) << 16);
                *(uint2*)&tbuf[col * 72 + row0] = packed;
            }
        }
        __syncthreads();   // tbuf writes visible (stage GLDS mostly landed by now)

        u16* outp = flav ? Bout : Aout;
        const int c = t >> 1, half = t & 1;
        u16* dst = outp + (size_t)c * PTOT + (size_t)ir * NN + k0 + half * 32;
        const u16* srcb = &tbuf[c * 72 + half * 32];
#pragma unroll
        for (int e = 0; e < 4; ++e)
            *(uint4*)(dst + e * 8) = *(const uint4*)(srcb + e * 8);

        cur ^= 1;
    }
}

// ---------------------------------------------------------------------------
// Kernel 3: per-channel GEMM  O[c][i][j] = sum_k A[c][i][k] * B[c][j][k]
// ---------------------------------------------------------------------------
__global__ __launch_bounds__(256) void cgemm(
    const u16* __restrict__ A, const u16* __restrict__ B, u16* __restrict__ O)
{
    __shared__ u16 ldsA[2][128 * 64];
    __shared__ u16 ldsB[2][128 * 64];

    const int t = threadIdx.x, l = t & 63, w = t >> 6;
    const int bx0 = blockIdx.x;
    const int bx  = (bx0 & 7) * 256 + (bx0 >> 3);
    const int c  = bx >> 4, ti = (bx >> 2) & 3, tj = bx & 3;
    const u16* Ab = A + (size_t)c * PTOT + (size_t)(ti * 128) * NN;
    const u16* Bb = B + (size_t)c * PTOT + (size_t)(tj * 128) * NN;

    const int lr8 = (w << 3) + (l >> 3);
    const int uu  = l & 7;

    auto stage = [&](int buf, int kt) {
#pragma unroll
        for (int ri = 0; ri < 4; ++ri) {
            int row = ri * 32 + lr8;
            const u16* sa = Ab + (size_t)row * NN + (kt << 6) + ((uu ^ (row & 7)) << 3);
            const u16* sb = Bb + (size_t)row * NN + (kt << 6) + ((uu ^ (row & 7)) << 3);
            u16* da = &ldsA[buf][(ri * 32 + (w << 3)) << 6];
            u16* db = &ldsB[buf][(ri * 32 + (w << 3)) << 6];
            GLDS16(sa, da);
            GLDS16(sb, db);
        }
    };

    const int wm = w >> 1, wn = w & 1;
    f32x4 zero4 = {0.f, 0.f, 0.f, 0.f};
    f32x4 acc[4][4];
#pragma unroll
    for (int mf = 0; mf < 4; ++mf)
#pragma unroll
        for (int nf = 0; nf < 4; ++nf) acc[mf][nf] = zero4;

    stage(0, 0);
    __syncthreads();
    int cur = 0;
    for (int kt = 0; kt < 8; ++kt) {
        if (kt < 7) stage(cur ^ 1, kt + 1);
        const u16* lA = ldsA[cur];
        const u16* lB = ldsB[cur];
#pragma unroll
        for (int kk = 0; kk < 2; ++kk) {
            bf16x8 af[4], bfr[4];
#pragma unroll
            for (int mf = 0; mf < 4; ++mf) {
                int row = (wm << 6) + (mf << 4) + (l & 15);
                int su  = ((kk << 2) + (l >> 4)) ^ (row & 7);
                af[mf] = *(const bf16x8*)&lA[(row << 6) + (su << 3)];
            }
#pragma unroll
            for (int nf = 0; nf < 4; ++nf) {
                int row = (wn << 6) + (nf << 4) + (l & 15);
                int su  = ((kk << 2) + (l >> 4)) ^ (row & 7);
                bfr[nf] = *(const bf16x8*)&lB[(row << 6) + (su << 3)];
            }
#pragma unroll
            for (int mf = 0; mf < 4; ++mf)
#pragma unroll
                for (int nf = 0; nf < 4; ++nf)
                    acc[mf][nf] = mfma16(af[mf], bfr[nf], acc[mf][nf]);
        }
        if (kt < 7) __syncthreads();
        cur ^= 1;
    }

    u16* Ob = O + (size_t)c * PTOT;
    const int i0 = ti * 128 + (wm << 6);
    const int j0 = tj * 128 + (wn << 6);
#pragma unroll
    for (int mf = 0; mf < 4; ++mf)
#pragma unroll
        for (int nf = 0; nf < 4; ++nf) {
            int jc = j0 + (nf << 4) + (l & 15);
#pragma unroll
            for (int rg = 0; rg < 4; ++rg) {
                int irow = i0 + (mf << 4) + ((l >> 4) << 2) + rg;
                Ob[(size_t)irow * NN + jc] = f2bf(acc[mf][nf][rg]);
            }
        }
}

// ---------------------------------------------------------------------------
// Kernel 4: out[p][co] = z[p][co] + sum_c O[c][p]*Wz[c][co] + b_z[co]
// Swapped MFMA roles; float4 epilogue; vectorized reg-transpose staging.
// ---------------------------------------------------------------------------
__global__ __launch_bounds__(256) void finalk(
    const u16* __restrict__ O, const u16* __restrict__ Wzt,
    const float* __restrict__ z, const float* __restrict__ bz,
    float* __restrict__ out)
{
    __shared__ u16 Ot[128 * 128];  // [p][c], swizzled

    const int t = threadIdx.x, l = t & 63, w = t >> 6;
    const int p0 = blockIdx.x << 7;

    // ---- phase 1: transpose O[c][p-tile] -> Ot[p][c] ----
    {
        const int po = t & 15;        // p-octet: p = po*8 .. +7
        const int uc = t >> 4;        // c-octet index 0..15, c0 = uc*8
        uint4 q[8];
#pragma unroll
        for (int cc = 0; cc < 8; ++cc)
            q[cc] = *(const uint4*)(O + (size_t)(uc * 8 + cc) * PTOT + p0 + po * 8);
#pragma unroll
        for (int e = 0; e < 8; ++e) {
            const int sh = (e & 1) * 16;
            const int wd = e >> 1;
            u32 h[8];
#pragma unroll
            for (int cc = 0; cc < 8; ++cc)
                h[cc] = (((const u32*)&q[cc])[wd] >> sh) & 0xffffu;
            uint4 o;
            o.x = h[0] | (h[1] << 16);
            o.y = h[2] | (h[3] << 16);
            o.z = h[4] | (h[5] << 16);
            o.w = h[6] | (h[7] << 16);
            int p  = po * 8 + e;
            int su = uc ^ (p & 15) ^ ((p >> 4) & 7);
            *(uint4*)&Ot[(p << 7) + (su << 3)] = o;
        }
    }
    __syncthreads();

    // ---- phase 2: MFMA. Wave w owns p-range [w*32, w*32+32). ----
    f32x4 zero4 = {0.f, 0.f, 0.f, 0.f};
    f32x4 acc[8][2];   // [mco][np]
#pragma unroll
    for (int m = 0; m < 8; ++m)
#pragma unroll
        for (int np = 0; np < 2; ++np) acc[m][np] = zero4;

#pragma unroll
    for (int kk = 0; kk < 4; ++kk) {
        bf16x8 af[8];
#pragma unroll
        for (int m = 0; m < 8; ++m) {
            int co = (m << 4) + (l & 15);
            af[m] = *(const bf16x8*)&Wzt[(co << 7) + (kk << 5) + ((l >> 4) << 3)];
        }
#pragma unroll
        for (int np = 0; np < 2; ++np) {
            int p  = (w << 5) + (np << 4) + (l & 15);
            int su = ((kk << 2) + (l >> 4)) ^ (p & 15) ^ ((p >> 4) & 7);
            bf16x8 bfr = *(const bf16x8*)&Ot[(p << 7) + (su << 3)];
#pragma unroll
            for (int m = 0; m < 8; ++m)
                acc[m][np] = mfma16(af[m], bfr, acc[m][np]);
        }
    }

    // ---- epilogue: float4 z-load + add + float4 store ----
#pragma unroll
    for (int m = 0; m < 8; ++m) {
        const int co4 = (m << 4) + ((l >> 4) << 2);
        const float4 bv = *(const float4*)&bz[co4];
#pragma unroll
        for (int np = 0; np < 2; ++np) {
            int p = p0 + (w << 5) + (np << 4) + (l & 15);
            size_t idx = (size_t)p * CZ + co4;
            float4 zv = *(const float4*)&z[idx];
            float4 ov;
            ov.x = zv.x + acc[m][np][0] + bv.x;
            ov.y = zv.y + acc[m][np][1] + bv.y;
            ov.z = zv.z + acc[m][np][2] + bv.z;
            ov.w = zv.w + acc[m][np][3] + bv.w;
            *(float4*)&out[idx] = ov;
        }
    }
}

// ---------------------------------------------------------------------------
extern "C" void kernel_launch(void* const* d_in, const int* in_sizes, int n_in,
                              void* d_out, int out_size, void* d_ws, size_t ws_size,
                              hipStream_t stream)
{
    const float* z    = (const float*)d_in[0];
    const float* mask = (const float*)d_in[1];
    const float* lnw  = (const float*)d_in[2];
    const float* lnb  = (const float*)d_in[3];
    const float* Wap  = (const float*)d_in[4];
    const float* bap  = (const float*)d_in[5];
    const float* Wag  = (const float*)d_in[6];
    const float* bag  = (const float*)d_in[7];
    const float* Wbp  = (const float*)d_in[8];
    const float* bbp  = (const float*)d_in[9];
    const float* Wbg  = (const float*)d_in[10];
    const float* bbg  = (const float*)d_in[11];
    const float* Wz   = (const float*)d_in[12];
    const float* bz   = (const float*)d_in[13];
    float* out = (float*)d_out;

    u16* A_t  = (u16*)d_ws;                       // [128][512][512] bf16, 67 MB
    u16* B_tt = A_t  + (size_t)CZ * PTOT;         // 67 MB
    u16* O_t  = B_tt + (size_t)CZ * PTOT;         // 67 MB
    u16* Wt   = O_t  + (size_t)CZ * PTOT;         // 5 x [128][128] bf16
    u16* Wzt  = Wt + 4 * 16384;
    u16* zn   = O_t;  // alias: zn dead before cgemm writes O_t

    prep_w<<<5, 256, 0, stream>>>(Wap, Wag, Wbp, Wbg, Wz, Wt);
    ln_k<<<4096, 256, 0, stream>>>(z, lnw, lnb, zn);
    proj_k<<<2048, 256, 0, stream>>>(zn, mask, Wt,
                                     bap, bag, bbp, bbg, A_t, B_tt);
    cgemm<<<2048, 256, 0, stream>>>(A_t, B_tt, O_t);
    finalk<<<2048, 256, 0, stream>>>(O_t, Wzt, z, bz, out);
}